// Round 11
// baseline (293.521 us; speedup 1.0000x reference)
//
#include <hip/hip_runtime.h>

#define BN_EPS 1e-5f

// ws layout (floats):
//   stats[0..28)   sum1      [28..56)  ssq1
//   stats[56..64)  sum2      [64..72)  ssq2
//   (BN finalize computed per-block in k4/k6 heads)
//   Psrc at ws+256          (N*32, rows 128B-aligned, cols 28..31 zeroed)
//   y1   at Psrc + N*32     (E*28)
//   y2   at y1 + E*28       (E*8)
//   Pdst OVERLAPS y2        (N*32 <= E*8; Pdst dead before K4 writes y2)

// K1: thread-per-node, 28 channels per thread, two blocks per 256-node range.
// W half staged in LDS, read as broadcast float4.
__global__ void k1_proj(const float* __restrict__ h, const float* __restrict__ W1,
                        float* __restrict__ Psrc, float* __restrict__ Pdst,
                        float* __restrict__ stats, int N) {
  __shared__ float lwk[3584];  // [c*128 + k] for this block's k-half
  if (blockIdx.x == 0 && threadIdx.x < 72) stats[threadIdx.x] = 0.f;
  const int half = blockIdx.x & 1;            // 0: src half (k 0..128), 1: dst half
  for (int j = threadIdx.x * 4; j < 3584; j += 1024) {
    const int c = j >> 7, k = j & 127;
    *(float4*)&lwk[j] = *(const float4*)(W1 + c * 268 + half * 128 + k);
  }
  __syncthreads();
  const int node = (blockIdx.x >> 1) * 256 + threadIdx.x;
  if (node >= N) return;

  const float4* __restrict__ h4 = (const float4*)(h + (size_t)node * 128);
  float acc[28];
#pragma unroll
  for (int c = 0; c < 28; c++) acc[c] = 0.f;

  for (int kk = 0; kk < 16; kk++) {
    const float4 a = h4[kk * 2];
    const float4 b = h4[kk * 2 + 1];
#pragma unroll
    for (int c = 0; c < 28; c++) {
      const float4 w0 = *(const float4*)&lwk[c * 128 + kk * 8];      // broadcast
      const float4 w1 = *(const float4*)&lwk[c * 128 + kk * 8 + 4];  // broadcast
      acc[c] += a.x * w0.x + a.y * w0.y + a.z * w0.z + a.w * w0.w
              + b.x * w1.x + b.y * w1.y + b.z * w1.z + b.w * w1.w;
    }
  }

  float4* po = (float4*)((half ? Pdst : Psrc) + (size_t)node * 32);
#pragma unroll
  for (int q = 0; q < 7; q++) {
    po[q] = make_float4(acc[q * 4], acc[q * 4 + 1], acc[q * 4 + 2], acc[q * 4 + 3]);
  }
  po[7] = make_float4(0.f, 0.f, 0.f, 0.f);  // zero pad (single-line gathers)
}

// K2: round-9 structure exactly (2 tiles/block, grid 1172 — measured 73us;
// round-10's 1-tile/block regressed to 102us from doubled per-block overhead).
__global__ __launch_bounds__(256)
void k2_edge(const float* __restrict__ Psrc, const float* __restrict__ Pdst,
             const float* __restrict__ ef,
             const int* __restrict__ src, const int* __restrict__ dst,
             const float* __restrict__ W1, const float* __restrict__ b1,
             float* __restrict__ y1, float* __restrict__ stats, int E) {
  __shared__ float lw[28][12];   // ef-part of W1 (cols 256..268)
  __shared__ float lb[28];
  __shared__ float tile[7168];   // 256 edges x 28 ch
  __shared__ float lsum[8][28], lssq[8][28];
  const int tid = threadIdx.x;
  for (int i = tid; i < 336; i += 256) lw[i / 12][i % 12] = W1[(i / 12) * 268 + 256 + (i % 12)];
  if (tid < 28) lb[tid] = b1[tid];
  if (tid < 224) { lsum[tid / 28][tid % 28] = 0.f; lssq[tid / 28][tid % 28] = 0.f; }
  __syncthreads();

  float sx = 0.f, sy = 0.f, sz = 0.f, sw = 0.f;
  float qx = 0.f, qy = 0.f, qz = 0.f, qw = 0.f;

  for (int t = 0; t < 2; t++) {
    const int base = (blockIdx.x * 2 + t) * 256;
    const int e = base + tid;
    if (e < E) {
      const int s = src[e], d = dst[e];
      const float4* __restrict__ pa4 = (const float4*)(Psrc + (size_t)s * 32);
      const float4* __restrict__ pb4 = (const float4*)(Pdst + (size_t)d * 32);
      const float4* __restrict__ e4 = (const float4*)(ef + (size_t)e * 12);
      float f[12];
#pragma unroll
      for (int q = 0; q < 3; q++) {
        const float4 v = e4[q];
        f[q * 4] = v.x; f[q * 4 + 1] = v.y; f[q * 4 + 2] = v.z; f[q * 4 + 3] = v.w;
      }
      float* tr = &tile[tid * 28];
#pragma unroll
      for (int q = 0; q < 7; q++) {
        const float4 ta = pa4[q];
        const float4 tb = pb4[q];
        float vv[4];
#pragma unroll
        for (int i2 = 0; i2 < 4; i2++) {
          const int c = q * 4 + i2;
          const float4* lw4 = (const float4*)(&lw[c][0]);  // uniform -> broadcast
          const float4 w0 = lw4[0], w1 = lw4[1], w2 = lw4[2];
          vv[i2] = lb[c]
              + f[0] * w0.x + f[1] * w0.y + f[2] * w0.z + f[3] * w0.w
              + f[4] * w1.x + f[5] * w1.y + f[6] * w1.z + f[7] * w1.w
              + f[8] * w2.x + f[9] * w2.y + f[10] * w2.z + f[11] * w2.w;
        }
        *(float4*)&tr[q * 4] = make_float4(vv[0] + ta.x + tb.x, vv[1] + ta.y + tb.y,
                                           vv[2] + ta.z + tb.z, vv[3] + ta.w + tb.w);
      }
    }
    __syncthreads();
    const int nval = min(256, E - base) * 28;   // negative if base>=E -> all skip
    if (tid < 224) {
      const size_t gbase = (size_t)base * 28;
#pragma unroll
      for (int i = 0; i < 8; i++) {
        const int jl = tid * 4 + i * 896;
        if (jl < nval) {
          const float4 v = *(const float4*)&tile[jl];        // consecutive lanes
          *(float4*)(y1 + gbase + jl) = v;                   // fully coalesced
          sx += v.x; sy += v.y; sz += v.z; sw += v.w;
          qx += v.x * v.x; qy += v.y * v.y; qz += v.z * v.z; qw += v.w * v.w;
        }
      }
    }
    __syncthreads();  // before next tile overwrite
  }

  if (tid < 224) {
    const int c0 = (tid * 4) % 28, a8 = tid / 28;   // 4-way contention per slot
    atomicAdd(&lsum[a8][c0], sx);     atomicAdd(&lssq[a8][c0], qx);
    atomicAdd(&lsum[a8][c0 + 1], sy); atomicAdd(&lssq[a8][c0 + 1], qy);
    atomicAdd(&lsum[a8][c0 + 2], sz); atomicAdd(&lssq[a8][c0 + 2], qz);
    atomicAdd(&lsum[a8][c0 + 3], sw); atomicAdd(&lssq[a8][c0 + 3], qw);
  }
  __syncthreads();
  if (tid < 28) {
    float S = 0.f, Q = 0.f;
#pragma unroll
    for (int a = 0; a < 8; a++) { S += lsum[a][tid]; Q += lssq[a][tid]; }
    atomicAdd(&stats[tid], S);
    atomicAdd(&stats[28 + tid], Q);
  }
}

// K4 REWRITE (quad-per-thread, barrier-free): 8-lane group owns one edge;
// lane q in [0,7) handles channels 4q..4q+4, q==7 idle (weights zeroed).
// y1 read is lane-consecutive (e*28+q*4 == base*28 + 4*lane) -> perfectly
// coalesced, NO LDS tile, NO inner barriers (old version: stage/barrier/
// compute serialization at 2.3 resident blocks). Cross-channel sum = 3
// shfl_down (4,2,1) inside the 8-lane group; q0's chain only reads lanes
// q1..q7 of its own group (q7 contributes 0). Lane q0 adds b2, stores y2,
// accumulates BN2 stats. Head computes BN1 scale/shift per-block (was k3).
__global__ __launch_bounds__(256)
void k4_l2(const float* __restrict__ y1, const float* __restrict__ statsRO,
           const float* __restrict__ W2, const float* __restrict__ b2,
           const float* __restrict__ g1, const float* __restrict__ be1,
           float* __restrict__ y2, float* __restrict__ statsW,
           int E, float invE) {
  __shared__ float4 w2q[8][7];   // w2q[o][q] = W2[o][4q..4q+4)
  __shared__ float scs[28], shs[28];
  __shared__ float lb2[8];
  const int tid = threadIdx.x;
  if (tid < 56) {
    w2q[tid / 7][tid % 7] = *(const float4*)(W2 + (tid / 7) * 28 + (tid % 7) * 4);
  } else if (tid >= 64 && tid < 92) {
    const int c = tid - 64;                       // BN1 finalize (was k3)
    const float mean = statsRO[c] * invE;
    const float var = statsRO[28 + c] * invE - mean * mean;
    const float sc = g1[c] * rsqrtf(var + BN_EPS);
    scs[c] = sc;
    shs[c] = be1[c] - mean * sc;
  } else if (tid >= 96 && tid < 104) {
    lb2[tid - 96] = b2[tid - 96];
  }
  __syncthreads();

  const int lane = tid & 63;
  const int q = lane & 7;        // channel quad (q==7 idle)
  const bool act = (q < 7);
  const int eg = lane >> 3;      // edge slot within wave (0..7)
  const int waveId = (blockIdx.x * 256 + tid) >> 6;
  const int nWaves = gridDim.x * 4;

  float4 sc4 = make_float4(0.f, 0.f, 0.f, 0.f);
  float4 sh4 = make_float4(0.f, 0.f, 0.f, 0.f);
  float4 wv[8];
#pragma unroll
  for (int o = 0; o < 8; o++) wv[o] = make_float4(0.f, 0.f, 0.f, 0.f);
  if (act) {
    sc4 = *(const float4*)&scs[q * 4];
    sh4 = *(const float4*)&shs[q * 4];
#pragma unroll
    for (int o = 0; o < 8; o++) wv[o] = w2q[o][q];
  }
  float bb[8];
#pragma unroll
  for (int o = 0; o < 8; o++) bb[o] = lb2[o];

  float as[8], aq[8];
#pragma unroll
  for (int o = 0; o < 8; o++) { as[o] = 0.f; aq[o] = 0.f; }

  for (int base = waveId * 8; base < E; base += nWaves * 8) {
    const int e = base + eg;     // all 8 lanes of a group share e
    float4 v = make_float4(0.f, 0.f, 0.f, 0.f);
    if (act && e < E) v = *(const float4*)(y1 + (size_t)e * 28 + q * 4);
    const float s0 = fmaxf(v.x * sc4.x + sh4.x, 0.f);
    const float s1 = fmaxf(v.y * sc4.y + sh4.y, 0.f);
    const float s2 = fmaxf(v.z * sc4.z + sh4.z, 0.f);
    const float s3 = fmaxf(v.w * sc4.w + sh4.w, 0.f);
    float r[8];
#pragma unroll
    for (int o = 0; o < 8; o++) {
      float p = s0 * wv[o].x + s1 * wv[o].y + s2 * wv[o].z + s3 * wv[o].w;
      p += __shfl_down(p, 4);
      p += __shfl_down(p, 2);
      p += __shfl_down(p, 1);
      r[o] = p;                  // full 28-channel sum, valid at q==0
    }
    if (q == 0 && e < E) {
      const float o0 = r[0] + bb[0], o1 = r[1] + bb[1], o2 = r[2] + bb[2], o3 = r[3] + bb[3];
      const float o4 = r[4] + bb[4], o5 = r[5] + bb[5], o6 = r[6] + bb[6], o7 = r[7] + bb[7];
      float4* yo = (float4*)(y2 + (size_t)e * 8);
      yo[0] = make_float4(o0, o1, o2, o3);
      yo[1] = make_float4(o4, o5, o6, o7);
      as[0] += o0; aq[0] += o0 * o0; as[1] += o1; aq[1] += o1 * o1;
      as[2] += o2; aq[2] += o2 * o2; as[3] += o3; aq[3] += o3 * o3;
      as[4] += o4; aq[4] += o4 * o4; as[5] += o5; aq[5] += o5 * o5;
      as[6] += o6; aq[6] += o6 * o6; as[7] += o7; aq[7] += o7 * o7;
    }
  }

  // stats reduce: full-wave shfl (non-q0 lanes hold 0), LDS, 16 atomics
#pragma unroll
  for (int o = 0; o < 8; o++) {
    for (int off = 32; off; off >>= 1) {
      as[o] += __shfl_down(as[o], off);
      aq[o] += __shfl_down(aq[o], off);
    }
  }
  __shared__ float redS[4][16];
  const int wave = tid >> 6;
  if (lane == 0) {
#pragma unroll
    for (int o = 0; o < 8; o++) { redS[wave][o] = as[o]; redS[wave][8 + o] = aq[o]; }
  }
  __syncthreads();
  if (tid < 16) {
    atomicAdd(&statsW[56 + tid], redS[0][tid] + redS[1][tid] + redS[2][tid] + redS[3][tid]);
  }
}

// K6: head computes BN2 scale/shift per-block (was k5), then
// out = relu(BN2(y2)) @ W3.T + b3
__global__ void k6_l3(const float* __restrict__ y2, const float* __restrict__ stats,
                      const float* __restrict__ g2, const float* __restrict__ be2,
                      const float* __restrict__ W3, const float* __restrict__ b3,
                      float* __restrict__ out, int E, float invE) {
  __shared__ float sc2[8], sh2[8], w3[8];
  __shared__ float b3s;
  if (threadIdx.x < 8) {
    const int c = threadIdx.x;
    const float mean = stats[56 + c] * invE;
    const float var = stats[64 + c] * invE - mean * mean;
    const float sc = g2[c] * rsqrtf(var + BN_EPS);
    sc2[c] = sc;
    sh2[c] = be2[c] - mean * sc;
    w3[c] = W3[c];
    if (c == 0) b3s = b3[0];
  }
  __syncthreads();
  const int e = blockIdx.x * blockDim.x + threadIdx.x;
  if (e >= E) return;
  const float4* p = (const float4*)(y2 + (size_t)e * 8);
  float4 a = p[0], b4 = p[1];
  float v[8] = {a.x, a.y, a.z, a.w, b4.x, b4.y, b4.z, b4.w};
  float acc = b3s;
#pragma unroll
  for (int o = 0; o < 8; o++) {
    float s = fmaxf(v[o] * sc2[o] + sh2[o], 0.f);
    acc += w3[o] * s;
  }
  out[e] = acc;
}

extern "C" void kernel_launch(void* const* d_in, const int* in_sizes, int n_in,
                              void* d_out, int out_size, void* d_ws, size_t ws_size,
                              hipStream_t stream) {
  const float* h   = (const float*)d_in[0];
  const float* ef  = (const float*)d_in[1];
  const int* src   = (const int*)d_in[2];
  const int* dst   = (const int*)d_in[3];
  const float* W1  = (const float*)d_in[4];
  const float* b1  = (const float*)d_in[5];
  const float* g1  = (const float*)d_in[6];
  const float* be1 = (const float*)d_in[7];
  const float* W2  = (const float*)d_in[8];
  const float* b2  = (const float*)d_in[9];
  const float* g2  = (const float*)d_in[10];
  const float* be2 = (const float*)d_in[11];
  const float* W3  = (const float*)d_in[12];
  const float* b3  = (const float*)d_in[13];
  float* out = (float*)d_out;

  const int N = in_sizes[0] / 128;
  const int E = in_sizes[2];
  const float invE = 1.0f / (float)E;

  float* ws = (float*)d_ws;
  float* stats = ws;                    // 256 floats reserved
  float* Psrc = ws + 256;               // N*32, 128B-aligned rows
  float* y1 = Psrc + (size_t)N * 32;    // E*28
  float* y2 = y1 + (size_t)E * 28;      // E*8
  float* Pdst = y2;                     // overlap: Pdst dead before K4 writes y2

  const int nodeBlocks = (N + 255) / 256;
  const int nTiles = (E + 255) / 256;   // 2344
  const int nPair = (nTiles + 1) / 2;   // 1172 (2 tiles per block in k2)
  k1_proj<<<nodeBlocks * 2, 256, 0, stream>>>(h, W1, Psrc, Pdst, stats, N);
  k2_edge<<<nPair, 256, 0, stream>>>(Psrc, Pdst, ef, src, dst, W1, b1, y1, stats, E);
  k4_l2<<<nTiles, 256, 0, stream>>>(y1, stats, W2, b2, g1, be1, y2, stats, E, invE);
  k6_l3<<<nTiles, 256, 0, stream>>>(y2, stats, g2, be2, W3, b3, out, E, invE);
}

// Round 12
// 278.888 us; speedup vs baseline: 1.0525x; 1.0525x over previous
//
#include <hip/hip_runtime.h>

#define BN_EPS 1e-5f

// ws layout (floats):
//   stats[0..28)   sum1      [28..56)  ssq1
//   stats[56..64)  sum2      [64..72)  ssq2
//   (BN finalize computed per-block in k4/k6 heads)
//   Psrc at ws+256          (N*32, rows 128B-aligned, cols 28..31 zeroed)
//   y1   at Psrc + N*32     (E*28)
//   y2   at y1 + E*28       (E*8)
//   Pdst OVERLAPS y2        (N*32 <= E*8; Pdst dead before K4 writes y2)

// K1: thread-per-node, 28 channels per thread, two blocks per 256-node range.
// REVERTED to uniform-pointer weight loads (s_load, SMEM pipe): the LDS-
// broadcast version issued 896 ds_read_b128/wave on the per-CU DS pipe
// (~27us, pipe-bound at 1.5 waves/SIMD); s_loads use the otherwise-idle
// scalar pipe and the kernel returns to VALU-bound (~5-12us).
__global__ void k1_proj(const float* __restrict__ h, const float* __restrict__ W1,
                        float* __restrict__ Psrc, float* __restrict__ Pdst,
                        float* __restrict__ stats, int N) {
  if (blockIdx.x == 0 && threadIdx.x < 72) stats[threadIdx.x] = 0.f;
  const int half = blockIdx.x & 1;            // 0: src half (k 0..128), 1: dst half
  const int node = (blockIdx.x >> 1) * 256 + threadIdx.x;
  if (node >= N) return;

  const float* __restrict__ wbase = W1 + half * 128;  // + c*268 + k
  const float4* __restrict__ h4 = (const float4*)(h + (size_t)node * 128);

  float acc[28];
#pragma unroll
  for (int c = 0; c < 28; c++) acc[c] = 0.f;

  for (int kk = 0; kk < 16; kk++) {
    const float4 a = h4[kk * 2];
    const float4 b = h4[kk * 2 + 1];
#pragma unroll
    for (int c = 0; c < 28; c++) {
      const float* w = wbase + c * 268 + kk * 8;  // uniform address -> s_load
      acc[c] += a.x * w[0] + a.y * w[1] + a.z * w[2] + a.w * w[3]
              + b.x * w[4] + b.y * w[5] + b.z * w[6] + b.w * w[7];
    }
  }

  float4* po = (float4*)((half ? Pdst : Psrc) + (size_t)node * 32);
#pragma unroll
  for (int q = 0; q < 7; q++) {
    po[q] = make_float4(acc[q * 4], acc[q * 4 + 1], acc[q * 4 + 2], acc[q * 4 + 3]);
  }
  po[7] = make_float4(0.f, 0.f, 0.f, 0.f);  // zero pad (single-line gathers)
}

// K2: round-9 structure exactly (2 tiles/block, grid 1172 — measured 73us).
__global__ __launch_bounds__(256)
void k2_edge(const float* __restrict__ Psrc, const float* __restrict__ Pdst,
             const float* __restrict__ ef,
             const int* __restrict__ src, const int* __restrict__ dst,
             const float* __restrict__ W1, const float* __restrict__ b1,
             float* __restrict__ y1, float* __restrict__ stats, int E) {
  __shared__ float lw[28][12];   // ef-part of W1 (cols 256..268)
  __shared__ float lb[28];
  __shared__ float tile[7168];   // 256 edges x 28 ch
  __shared__ float lsum[8][28], lssq[8][28];
  const int tid = threadIdx.x;
  for (int i = tid; i < 336; i += 256) lw[i / 12][i % 12] = W1[(i / 12) * 268 + 256 + (i % 12)];
  if (tid < 28) lb[tid] = b1[tid];
  if (tid < 224) { lsum[tid / 28][tid % 28] = 0.f; lssq[tid / 28][tid % 28] = 0.f; }
  __syncthreads();

  float sx = 0.f, sy = 0.f, sz = 0.f, sw = 0.f;
  float qx = 0.f, qy = 0.f, qz = 0.f, qw = 0.f;

  for (int t = 0; t < 2; t++) {
    const int base = (blockIdx.x * 2 + t) * 256;
    const int e = base + tid;
    if (e < E) {
      const int s = src[e], d = dst[e];
      const float4* __restrict__ pa4 = (const float4*)(Psrc + (size_t)s * 32);
      const float4* __restrict__ pb4 = (const float4*)(Pdst + (size_t)d * 32);
      const float4* __restrict__ e4 = (const float4*)(ef + (size_t)e * 12);
      float f[12];
#pragma unroll
      for (int q = 0; q < 3; q++) {
        const float4 v = e4[q];
        f[q * 4] = v.x; f[q * 4 + 1] = v.y; f[q * 4 + 2] = v.z; f[q * 4 + 3] = v.w;
      }
      float* tr = &tile[tid * 28];
#pragma unroll
      for (int q = 0; q < 7; q++) {
        const float4 ta = pa4[q];
        const float4 tb = pb4[q];
        float vv[4];
#pragma unroll
        for (int i2 = 0; i2 < 4; i2++) {
          const int c = q * 4 + i2;
          const float4* lw4 = (const float4*)(&lw[c][0]);  // uniform -> broadcast
          const float4 w0 = lw4[0], w1 = lw4[1], w2 = lw4[2];
          vv[i2] = lb[c]
              + f[0] * w0.x + f[1] * w0.y + f[2] * w0.z + f[3] * w0.w
              + f[4] * w1.x + f[5] * w1.y + f[6] * w1.z + f[7] * w1.w
              + f[8] * w2.x + f[9] * w2.y + f[10] * w2.z + f[11] * w2.w;
        }
        *(float4*)&tr[q * 4] = make_float4(vv[0] + ta.x + tb.x, vv[1] + ta.y + tb.y,
                                           vv[2] + ta.z + tb.z, vv[3] + ta.w + tb.w);
      }
    }
    __syncthreads();
    const int nval = min(256, E - base) * 28;   // negative if base>=E -> all skip
    if (tid < 224) {
      const size_t gbase = (size_t)base * 28;
#pragma unroll
      for (int i = 0; i < 8; i++) {
        const int jl = tid * 4 + i * 896;
        if (jl < nval) {
          const float4 v = *(const float4*)&tile[jl];        // consecutive lanes
          *(float4*)(y1 + gbase + jl) = v;                   // fully coalesced
          sx += v.x; sy += v.y; sz += v.z; sw += v.w;
          qx += v.x * v.x; qy += v.y * v.y; qz += v.z * v.z; qw += v.w * v.w;
        }
      }
    }
    __syncthreads();  // before next tile overwrite
  }

  if (tid < 224) {
    const int c0 = (tid * 4) % 28, a8 = tid / 28;   // 4-way contention per slot
    atomicAdd(&lsum[a8][c0], sx);     atomicAdd(&lssq[a8][c0], qx);
    atomicAdd(&lsum[a8][c0 + 1], sy); atomicAdd(&lssq[a8][c0 + 1], qy);
    atomicAdd(&lsum[a8][c0 + 2], sz); atomicAdd(&lssq[a8][c0 + 2], qz);
    atomicAdd(&lsum[a8][c0 + 3], sw); atomicAdd(&lssq[a8][c0 + 3], qw);
  }
  __syncthreads();
  if (tid < 28) {
    float S = 0.f, Q = 0.f;
#pragma unroll
    for (int a = 0; a < 8; a++) { S += lsum[a][tid]; Q += lssq[a][tid]; }
    atomicAdd(&stats[tid], S);
    atomicAdd(&stats[28 + tid], Q);
  }
}

// K4: REVERTED to round-10 LDS-tile structure (shfl version regressed 50->90:
// __shfl_down is a DS-pipe op on CDNA — 24 ds_bpermute per 8 edges moved the
// bottleneck onto LDS). Head computes BN1 scale/shift per-block (was k3).
__global__ void k4_l2(const float* __restrict__ y1, const float* __restrict__ statsRO,
                      const float* __restrict__ W2, const float* __restrict__ b2,
                      const float* __restrict__ g1, const float* __restrict__ be1,
                      float* __restrict__ y2, float* __restrict__ statsW,
                      int E, float invE) {
  __shared__ float tile[7168];
  __shared__ float4 w2q[8][7];   // w2q[o][q] = W2[o][4q..4q+4)
  __shared__ float scs[28], shs[28];
  __shared__ float lb2[8];
  const int tid = threadIdx.x;
  if (tid < 56) {
    w2q[tid / 7][tid % 7] = *(const float4*)(W2 + (tid / 7) * 28 + (tid % 7) * 4);
  } else if (tid >= 64 && tid < 92) {
    const int c = tid - 64;                       // BN1 finalize (was k3)
    const float mean = statsRO[c] * invE;
    const float var = statsRO[28 + c] * invE - mean * mean;
    const float sc = g1[c] * rsqrtf(var + BN_EPS);
    scs[c] = sc;
    shs[c] = be1[c] - mean * sc;
  } else if (tid >= 96 && tid < 104) {
    lb2[tid - 96] = b2[tid - 96];
  }
  float as[8], aq[8];
#pragma unroll
  for (int o = 0; o < 8; o++) { as[o] = 0.f; aq[o] = 0.f; }

  for (int t = 0; t < 2; t++) {
    const int base = (blockIdx.x * 2 + t) * 256;
    const int nval = min(256, E - base) * 28;
    __syncthreads();  // weights/scale visible (t=0) / previous compute done (t=1)
    if (tid < 224) {
      const size_t gbase = (size_t)base * 28;
#pragma unroll
      for (int i = 0; i < 8; i++) {
        const int jl = tid * 4 + i * 896;
        if (jl < nval) *(float4*)&tile[jl] = *(const float4*)(y1 + gbase + jl);
      }
    }
    __syncthreads();
    const int e = base + tid;
    if (e < E) {
      float accv[8];
#pragma unroll
      for (int o = 0; o < 8; o++) accv[o] = lb2[o];
      const float* tr = &tile[tid * 28];
#pragma unroll
      for (int q = 0; q < 7; q++) {
        const float4 sv = *(const float4*)&tr[q * 4];
        const float4 sc = *(const float4*)&scs[q * 4];   // broadcast
        const float4 sh = *(const float4*)&shs[q * 4];   // broadcast
        const float s0 = fmaxf(sv.x * sc.x + sh.x, 0.f);
        const float s1 = fmaxf(sv.y * sc.y + sh.y, 0.f);
        const float s2 = fmaxf(sv.z * sc.z + sh.z, 0.f);
        const float s3 = fmaxf(sv.w * sc.w + sh.w, 0.f);
#pragma unroll
        for (int o = 0; o < 8; o++) {
          const float4 w = w2q[o][q];                    // broadcast
          accv[o] += s0 * w.x + s1 * w.y + s2 * w.z + s3 * w.w;
        }
      }
      float4* yo = (float4*)(y2 + (size_t)e * 8);
      yo[0] = make_float4(accv[0], accv[1], accv[2], accv[3]);
      yo[1] = make_float4(accv[4], accv[5], accv[6], accv[7]);
#pragma unroll
      for (int o = 0; o < 8; o++) { as[o] += accv[o]; aq[o] += accv[o] * accv[o]; }
    }
  }

#pragma unroll
  for (int o = 0; o < 8; o++) {
    for (int off = 32; off; off >>= 1) {
      as[o] += __shfl_down(as[o], off);
      aq[o] += __shfl_down(aq[o], off);
    }
  }
  __shared__ float redS[4][16];
  const int wave = tid >> 6, lane = tid & 63;
  if (lane == 0) {
#pragma unroll
    for (int o = 0; o < 8; o++) { redS[wave][o] = as[o]; redS[wave][8 + o] = aq[o]; }
  }
  __syncthreads();
  if (tid < 16) {
    atomicAdd(&statsW[56 + tid], redS[0][tid] + redS[1][tid] + redS[2][tid] + redS[3][tid]);
  }
}

// K6: head computes BN2 scale/shift per-block (was k5), then
// out = relu(BN2(y2)) @ W3.T + b3
__global__ void k6_l3(const float* __restrict__ y2, const float* __restrict__ stats,
                      const float* __restrict__ g2, const float* __restrict__ be2,
                      const float* __restrict__ W3, const float* __restrict__ b3,
                      float* __restrict__ out, int E, float invE) {
  __shared__ float sc2[8], sh2[8], w3[8];
  __shared__ float b3s;
  if (threadIdx.x < 8) {
    const int c = threadIdx.x;
    const float mean = stats[56 + c] * invE;
    const float var = stats[64 + c] * invE - mean * mean;
    const float sc = g2[c] * rsqrtf(var + BN_EPS);
    sc2[c] = sc;
    sh2[c] = be2[c] - mean * sc;
    w3[c] = W3[c];
    if (c == 0) b3s = b3[0];
  }
  __syncthreads();
  const int e = blockIdx.x * blockDim.x + threadIdx.x;
  if (e >= E) return;
  const float4* p = (const float4*)(y2 + (size_t)e * 8);
  float4 a = p[0], b4 = p[1];
  float v[8] = {a.x, a.y, a.z, a.w, b4.x, b4.y, b4.z, b4.w};
  float acc = b3s;
#pragma unroll
  for (int o = 0; o < 8; o++) {
    float s = fmaxf(v[o] * sc2[o] + sh2[o], 0.f);
    acc += w3[o] * s;
  }
  out[e] = acc;
}

extern "C" void kernel_launch(void* const* d_in, const int* in_sizes, int n_in,
                              void* d_out, int out_size, void* d_ws, size_t ws_size,
                              hipStream_t stream) {
  const float* h   = (const float*)d_in[0];
  const float* ef  = (const float*)d_in[1];
  const int* src   = (const int*)d_in[2];
  const int* dst   = (const int*)d_in[3];
  const float* W1  = (const float*)d_in[4];
  const float* b1  = (const float*)d_in[5];
  const float* g1  = (const float*)d_in[6];
  const float* be1 = (const float*)d_in[7];
  const float* W2  = (const float*)d_in[8];
  const float* b2  = (const float*)d_in[9];
  const float* g2  = (const float*)d_in[10];
  const float* be2 = (const float*)d_in[11];
  const float* W3  = (const float*)d_in[12];
  const float* b3  = (const float*)d_in[13];
  float* out = (float*)d_out;

  const int N = in_sizes[0] / 128;
  const int E = in_sizes[2];
  const float invE = 1.0f / (float)E;

  float* ws = (float*)d_ws;
  float* stats = ws;                    // 256 floats reserved
  float* Psrc = ws + 256;               // N*32, 128B-aligned rows
  float* y1 = Psrc + (size_t)N * 32;    // E*28
  float* y2 = y1 + (size_t)E * 28;      // E*8
  float* Pdst = y2;                     // overlap: Pdst dead before K4 writes y2

  const int nodeBlocks = (N + 255) / 256;
  const int nTiles = (E + 255) / 256;   // 2344
  const int nPair = (nTiles + 1) / 2;   // 1172 (2 tiles per block in k2/k4)
  k1_proj<<<nodeBlocks * 2, 256, 0, stream>>>(h, W1, Psrc, Pdst, stats, N);
  k2_edge<<<nPair, 256, 0, stream>>>(Psrc, Pdst, ef, src, dst, W1, b1, y1, stats, E);
  k4_l2<<<nPair, 256, 0, stream>>>(y1, stats, W2, b2, g1, be1, y2, stats, E, invE);
  k6_l3<<<nTiles, 256, 0, stream>>>(y2, stats, g2, be2, W3, b3, out, E, invE);
}

// Round 13
// 264.694 us; speedup vs baseline: 1.1089x; 1.0536x over previous
//
#include <hip/hip_runtime.h>

#define BN_EPS 1e-5f

// ws layout (floats):
//   stats[0..28)   sum1      [28..56)  ssq1
//   stats[56..64)  sum2      [64..72)  ssq2
//   (BN finalize computed per-block in k4/k6 heads)
//   Psrc at ws+256          (N*32, rows 128B-aligned, cols 28..31 zeroed)
//   y1   at Psrc + N*32     (E*28)
//   y2   at y1 + E*28       (E*8)
//   Pdst OVERLAPS y2        (N*32 <= E*8; Pdst dead before K4 writes y2)

// K1 v3: LDS-broadcast weights (s_load version measured 75us — lgkmcnt-drain
// on out-of-order SMEM returns; LDS version ~50us) + 2 NODES PER THREAD to
// halve DS-pipe instructions per node (the LDS version's bound: 896
// ds_read_b128/wave serving one node each). 128-thread blocks keep grid at
// 392 (256-thread 2-node blocks would leave 60 CUs idle). Per wave now:
// 896 DS reads (10.7Kcy) serve 2 nodes of FMA (14.3Kcy VALU) — balanced.
__global__ __launch_bounds__(128)
void k1_proj(const float* __restrict__ h, const float* __restrict__ W1,
             float* __restrict__ Psrc, float* __restrict__ Pdst,
             float* __restrict__ stats, int N) {
  __shared__ float lwk[3584];  // [c*128 + k] for this block's k-half
  if (blockIdx.x == 0 && threadIdx.x < 72) stats[threadIdx.x] = 0.f;
  const int half = blockIdx.x & 1;            // 0: src half (k 0..128), 1: dst half
  for (int j = threadIdx.x * 4; j < 3584; j += 512) {
    const int c = j >> 7, k = j & 127;
    *(float4*)&lwk[j] = *(const float4*)(W1 + c * 268 + half * 128 + k);
  }
  __syncthreads();

  const int nodeA = (blockIdx.x >> 1) * 256 + threadIdx.x;
  const int nodeB = nodeA + 128;
  const bool vA = (nodeA < N), vB = (nodeB < N);
  if (!vA) return;  // nodes ascend with tid; !vA implies !vB

  const float4* __restrict__ hA = (const float4*)(h + (size_t)nodeA * 128);
  const float4* __restrict__ hB = (const float4*)(h + (size_t)nodeB * 128);

  float accA[28], accB[28];
#pragma unroll
  for (int c = 0; c < 28; c++) { accA[c] = 0.f; accB[c] = 0.f; }

  for (int kk = 0; kk < 16; kk++) {
    const float4 a0 = hA[kk * 2];
    const float4 a1 = hA[kk * 2 + 1];
    float4 b0 = make_float4(0.f, 0.f, 0.f, 0.f);
    float4 b1 = make_float4(0.f, 0.f, 0.f, 0.f);
    if (vB) { b0 = hB[kk * 2]; b1 = hB[kk * 2 + 1]; }
#pragma unroll
    for (int c = 0; c < 28; c++) {
      const float4 w0 = *(const float4*)&lwk[c * 128 + kk * 8];      // broadcast
      const float4 w1 = *(const float4*)&lwk[c * 128 + kk * 8 + 4];  // broadcast
      accA[c] += a0.x * w0.x + a0.y * w0.y + a0.z * w0.z + a0.w * w0.w
               + a1.x * w1.x + a1.y * w1.y + a1.z * w1.z + a1.w * w1.w;
      accB[c] += b0.x * w0.x + b0.y * w0.y + b0.z * w0.z + b0.w * w0.w
               + b1.x * w1.x + b1.y * w1.y + b1.z * w1.z + b1.w * w1.w;
    }
  }

  float* __restrict__ P = half ? Pdst : Psrc;
  float4* poA = (float4*)(P + (size_t)nodeA * 32);
#pragma unroll
  for (int q = 0; q < 7; q++) {
    poA[q] = make_float4(accA[q * 4], accA[q * 4 + 1], accA[q * 4 + 2], accA[q * 4 + 3]);
  }
  poA[7] = make_float4(0.f, 0.f, 0.f, 0.f);  // zero pad (single-line gathers)
  if (vB) {
    float4* poB = (float4*)(P + (size_t)nodeB * 32);
#pragma unroll
    for (int q = 0; q < 7; q++) {
      poB[q] = make_float4(accB[q * 4], accB[q * 4 + 1], accB[q * 4 + 2], accB[q * 4 + 3]);
    }
    poB[7] = make_float4(0.f, 0.f, 0.f, 0.f);
  }
}

// K2: round-9 structure exactly (2 tiles/block, grid 1172 — measured 73us).
__global__ __launch_bounds__(256)
void k2_edge(const float* __restrict__ Psrc, const float* __restrict__ Pdst,
             const float* __restrict__ ef,
             const int* __restrict__ src, const int* __restrict__ dst,
             const float* __restrict__ W1, const float* __restrict__ b1,
             float* __restrict__ y1, float* __restrict__ stats, int E) {
  __shared__ float lw[28][12];   // ef-part of W1 (cols 256..268)
  __shared__ float lb[28];
  __shared__ float tile[7168];   // 256 edges x 28 ch
  __shared__ float lsum[8][28], lssq[8][28];
  const int tid = threadIdx.x;
  for (int i = tid; i < 336; i += 256) lw[i / 12][i % 12] = W1[(i / 12) * 268 + 256 + (i % 12)];
  if (tid < 28) lb[tid] = b1[tid];
  if (tid < 224) { lsum[tid / 28][tid % 28] = 0.f; lssq[tid / 28][tid % 28] = 0.f; }
  __syncthreads();

  float sx = 0.f, sy = 0.f, sz = 0.f, sw = 0.f;
  float qx = 0.f, qy = 0.f, qz = 0.f, qw = 0.f;

  for (int t = 0; t < 2; t++) {
    const int base = (blockIdx.x * 2 + t) * 256;
    const int e = base + tid;
    if (e < E) {
      const int s = src[e], d = dst[e];
      const float4* __restrict__ pa4 = (const float4*)(Psrc + (size_t)s * 32);
      const float4* __restrict__ pb4 = (const float4*)(Pdst + (size_t)d * 32);
      const float4* __restrict__ e4 = (const float4*)(ef + (size_t)e * 12);
      float f[12];
#pragma unroll
      for (int q = 0; q < 3; q++) {
        const float4 v = e4[q];
        f[q * 4] = v.x; f[q * 4 + 1] = v.y; f[q * 4 + 2] = v.z; f[q * 4 + 3] = v.w;
      }
      float* tr = &tile[tid * 28];
#pragma unroll
      for (int q = 0; q < 7; q++) {
        const float4 ta = pa4[q];
        const float4 tb = pb4[q];
        float vv[4];
#pragma unroll
        for (int i2 = 0; i2 < 4; i2++) {
          const int c = q * 4 + i2;
          const float4* lw4 = (const float4*)(&lw[c][0]);  // uniform -> broadcast
          const float4 w0 = lw4[0], w1 = lw4[1], w2 = lw4[2];
          vv[i2] = lb[c]
              + f[0] * w0.x + f[1] * w0.y + f[2] * w0.z + f[3] * w0.w
              + f[4] * w1.x + f[5] * w1.y + f[6] * w1.z + f[7] * w1.w
              + f[8] * w2.x + f[9] * w2.y + f[10] * w2.z + f[11] * w2.w;
        }
        *(float4*)&tr[q * 4] = make_float4(vv[0] + ta.x + tb.x, vv[1] + ta.y + tb.y,
                                           vv[2] + ta.z + tb.z, vv[3] + ta.w + tb.w);
      }
    }
    __syncthreads();
    const int nval = min(256, E - base) * 28;   // negative if base>=E -> all skip
    if (tid < 224) {
      const size_t gbase = (size_t)base * 28;
#pragma unroll
      for (int i = 0; i < 8; i++) {
        const int jl = tid * 4 + i * 896;
        if (jl < nval) {
          const float4 v = *(const float4*)&tile[jl];        // consecutive lanes
          *(float4*)(y1 + gbase + jl) = v;                   // fully coalesced
          sx += v.x; sy += v.y; sz += v.z; sw += v.w;
          qx += v.x * v.x; qy += v.y * v.y; qz += v.z * v.z; qw += v.w * v.w;
        }
      }
    }
    __syncthreads();  // before next tile overwrite
  }

  if (tid < 224) {
    const int c0 = (tid * 4) % 28, a8 = tid / 28;   // 4-way contention per slot
    atomicAdd(&lsum[a8][c0], sx);     atomicAdd(&lssq[a8][c0], qx);
    atomicAdd(&lsum[a8][c0 + 1], sy); atomicAdd(&lssq[a8][c0 + 1], qy);
    atomicAdd(&lsum[a8][c0 + 2], sz); atomicAdd(&lssq[a8][c0 + 2], qz);
    atomicAdd(&lsum[a8][c0 + 3], sw); atomicAdd(&lssq[a8][c0 + 3], qw);
  }
  __syncthreads();
  if (tid < 28) {
    float S = 0.f, Q = 0.f;
#pragma unroll
    for (int a = 0; a < 8; a++) { S += lsum[a][tid]; Q += lssq[a][tid]; }
    atomicAdd(&stats[tid], S);
    atomicAdd(&stats[28 + tid], Q);
  }
}

// K4: LDS-tile structure + BN1 finalize head (round-12, measured good).
__global__ void k4_l2(const float* __restrict__ y1, const float* __restrict__ statsRO,
                      const float* __restrict__ W2, const float* __restrict__ b2,
                      const float* __restrict__ g1, const float* __restrict__ be1,
                      float* __restrict__ y2, float* __restrict__ statsW,
                      int E, float invE) {
  __shared__ float tile[7168];
  __shared__ float4 w2q[8][7];   // w2q[o][q] = W2[o][4q..4q+4)
  __shared__ float scs[28], shs[28];
  __shared__ float lb2[8];
  const int tid = threadIdx.x;
  if (tid < 56) {
    w2q[tid / 7][tid % 7] = *(const float4*)(W2 + (tid / 7) * 28 + (tid % 7) * 4);
  } else if (tid >= 64 && tid < 92) {
    const int c = tid - 64;                       // BN1 finalize (was k3)
    const float mean = statsRO[c] * invE;
    const float var = statsRO[28 + c] * invE - mean * mean;
    const float sc = g1[c] * rsqrtf(var + BN_EPS);
    scs[c] = sc;
    shs[c] = be1[c] - mean * sc;
  } else if (tid >= 96 && tid < 104) {
    lb2[tid - 96] = b2[tid - 96];
  }
  float as[8], aq[8];
#pragma unroll
  for (int o = 0; o < 8; o++) { as[o] = 0.f; aq[o] = 0.f; }

  for (int t = 0; t < 2; t++) {
    const int base = (blockIdx.x * 2 + t) * 256;
    const int nval = min(256, E - base) * 28;
    __syncthreads();  // weights/scale visible (t=0) / previous compute done (t=1)
    if (tid < 224) {
      const size_t gbase = (size_t)base * 28;
#pragma unroll
      for (int i = 0; i < 8; i++) {
        const int jl = tid * 4 + i * 896;
        if (jl < nval) *(float4*)&tile[jl] = *(const float4*)(y1 + gbase + jl);
      }
    }
    __syncthreads();
    const int e = base + tid;
    if (e < E) {
      float accv[8];
#pragma unroll
      for (int o = 0; o < 8; o++) accv[o] = lb2[o];
      const float* tr = &tile[tid * 28];
#pragma unroll
      for (int q = 0; q < 7; q++) {
        const float4 sv = *(const float4*)&tr[q * 4];
        const float4 sc = *(const float4*)&scs[q * 4];   // broadcast
        const float4 sh = *(const float4*)&shs[q * 4];   // broadcast
        const float s0 = fmaxf(sv.x * sc.x + sh.x, 0.f);
        const float s1 = fmaxf(sv.y * sc.y + sh.y, 0.f);
        const float s2 = fmaxf(sv.z * sc.z + sh.z, 0.f);
        const float s3 = fmaxf(sv.w * sc.w + sh.w, 0.f);
#pragma unroll
        for (int o = 0; o < 8; o++) {
          const float4 w = w2q[o][q];                    // broadcast
          accv[o] += s0 * w.x + s1 * w.y + s2 * w.z + s3 * w.w;
        }
      }
      float4* yo = (float4*)(y2 + (size_t)e * 8);
      yo[0] = make_float4(accv[0], accv[1], accv[2], accv[3]);
      yo[1] = make_float4(accv[4], accv[5], accv[6], accv[7]);
#pragma unroll
      for (int o = 0; o < 8; o++) { as[o] += accv[o]; aq[o] += accv[o] * accv[o]; }
    }
  }

#pragma unroll
  for (int o = 0; o < 8; o++) {
    for (int off = 32; off; off >>= 1) {
      as[o] += __shfl_down(as[o], off);
      aq[o] += __shfl_down(aq[o], off);
    }
  }
  __shared__ float redS[4][16];
  const int wave = tid >> 6, lane = tid & 63;
  if (lane == 0) {
#pragma unroll
    for (int o = 0; o < 8; o++) { redS[wave][o] = as[o]; redS[wave][8 + o] = aq[o]; }
  }
  __syncthreads();
  if (tid < 16) {
    atomicAdd(&statsW[56 + tid], redS[0][tid] + redS[1][tid] + redS[2][tid] + redS[3][tid]);
  }
}

// K6: head computes BN2 scale/shift per-block (was k5), then
// out = relu(BN2(y2)) @ W3.T + b3
__global__ void k6_l3(const float* __restrict__ y2, const float* __restrict__ stats,
                      const float* __restrict__ g2, const float* __restrict__ be2,
                      const float* __restrict__ W3, const float* __restrict__ b3,
                      float* __restrict__ out, int E, float invE) {
  __shared__ float sc2[8], sh2[8], w3[8];
  __shared__ float b3s;
  if (threadIdx.x < 8) {
    const int c = threadIdx.x;
    const float mean = stats[56 + c] * invE;
    const float var = stats[64 + c] * invE - mean * mean;
    const float sc = g2[c] * rsqrtf(var + BN_EPS);
    sc2[c] = sc;
    sh2[c] = be2[c] - mean * sc;
    w3[c] = W3[c];
    if (c == 0) b3s = b3[0];
  }
  __syncthreads();
  const int e = blockIdx.x * blockDim.x + threadIdx.x;
  if (e >= E) return;
  const float4* p = (const float4*)(y2 + (size_t)e * 8);
  float4 a = p[0], b4 = p[1];
  float v[8] = {a.x, a.y, a.z, a.w, b4.x, b4.y, b4.z, b4.w};
  float acc = b3s;
#pragma unroll
  for (int o = 0; o < 8; o++) {
    float s = fmaxf(v[o] * sc2[o] + sh2[o], 0.f);
    acc += w3[o] * s;
  }
  out[e] = acc;
}

extern "C" void kernel_launch(void* const* d_in, const int* in_sizes, int n_in,
                              void* d_out, int out_size, void* d_ws, size_t ws_size,
                              hipStream_t stream) {
  const float* h   = (const float*)d_in[0];
  const float* ef  = (const float*)d_in[1];
  const int* src   = (const int*)d_in[2];
  const int* dst   = (const int*)d_in[3];
  const float* W1  = (const float*)d_in[4];
  const float* b1  = (const float*)d_in[5];
  const float* g1  = (const float*)d_in[6];
  const float* be1 = (const float*)d_in[7];
  const float* W2  = (const float*)d_in[8];
  const float* b2  = (const float*)d_in[9];
  const float* g2  = (const float*)d_in[10];
  const float* be2 = (const float*)d_in[11];
  const float* W3  = (const float*)d_in[12];
  const float* b3  = (const float*)d_in[13];
  float* out = (float*)d_out;

  const int N = in_sizes[0] / 128;
  const int E = in_sizes[2];
  const float invE = 1.0f / (float)E;

  float* ws = (float*)d_ws;
  float* stats = ws;                    // 256 floats reserved
  float* Psrc = ws + 256;               // N*32, 128B-aligned rows
  float* y1 = Psrc + (size_t)N * 32;    // E*28
  float* y2 = y1 + (size_t)E * 28;      // E*8
  float* Pdst = y2;                     // overlap: Pdst dead before K4 writes y2

  const int nodeBlocks = (N + 255) / 256;  // 196 (256 nodes per block, 2 per thread)
  const int nTiles = (E + 255) / 256;   // 2344
  const int nPair = (nTiles + 1) / 2;   // 1172 (2 tiles per block in k2/k4)
  k1_proj<<<nodeBlocks * 2, 128, 0, stream>>>(h, W1, Psrc, Pdst, stats, N);
  k2_edge<<<nPair, 256, 0, stream>>>(Psrc, Pdst, ef, src, dst, W1, b1, y1, stats, E);
  k4_l2<<<nPair, 256, 0, stream>>>(y1, stats, W2, b2, g1, be1, y2, stats, E, invE);
  k6_l3<<<nTiles, 256, 0, stream>>>(y2, stats, g2, be2, W3, b3, out, E, invE);
}

// Round 15
// 254.300 us; speedup vs baseline: 1.1542x; 1.0409x over previous
//
#include <hip/hip_runtime.h>

#define BN_EPS 1e-5f

// ws layout (floats):
//   stats[0..28) sum1  [28..56) ssq1  [56..64) sum2  [64..72) ssq2
//   (BN finalize computed per-block in k4/k6 heads)
//   Psrc at ws+256 (N*32, 128B rows, cols 28..31 zeroed)
//   y1 at Psrc+N*32 (E*28); y2 at y1+E*28 (E*8); Pdst OVERLAPS y2.
// NOTE: cooperative launch is NOT usable here — the harness graph-captures
// the stream and hipLaunchCooperativeKernel invalidates the capture (round-14
// container failure). Regular launches only.

// K1: 2 nodes/thread, 128-thread blocks, LDS-broadcast weights (round-13,
// measured good; s_load variant measured 75us — lgkmcnt drains).
__global__ __launch_bounds__(128)
void k1_proj(const float* __restrict__ h, const float* __restrict__ W1,
             float* __restrict__ Psrc, float* __restrict__ Pdst,
             float* __restrict__ stats, int N) {
  __shared__ float lwk[3584];
  if (blockIdx.x == 0 && threadIdx.x < 72) stats[threadIdx.x] = 0.f;
  const int half = blockIdx.x & 1;
  for (int j = threadIdx.x * 4; j < 3584; j += 512) {
    const int c = j >> 7, k = j & 127;
    *(float4*)&lwk[j] = *(const float4*)(W1 + c * 268 + half * 128 + k);
  }
  __syncthreads();
  const int nodeA = (blockIdx.x >> 1) * 256 + threadIdx.x;
  const int nodeB = nodeA + 128;
  const bool vA = (nodeA < N), vB = (nodeB < N);
  if (!vA) return;
  const float4* __restrict__ hA = (const float4*)(h + (size_t)nodeA * 128);
  const float4* __restrict__ hB = (const float4*)(h + (size_t)nodeB * 128);
  float accA[28], accB[28];
#pragma unroll
  for (int c = 0; c < 28; c++) { accA[c] = 0.f; accB[c] = 0.f; }
  for (int kk = 0; kk < 16; kk++) {
    const float4 a0 = hA[kk * 2];
    const float4 a1 = hA[kk * 2 + 1];
    float4 b0 = make_float4(0.f, 0.f, 0.f, 0.f);
    float4 b1v = make_float4(0.f, 0.f, 0.f, 0.f);
    if (vB) { b0 = hB[kk * 2]; b1v = hB[kk * 2 + 1]; }
#pragma unroll
    for (int c = 0; c < 28; c++) {
      const float4 w0 = *(const float4*)&lwk[c * 128 + kk * 8];
      const float4 w1 = *(const float4*)&lwk[c * 128 + kk * 8 + 4];
      accA[c] += a0.x * w0.x + a0.y * w0.y + a0.z * w0.z + a0.w * w0.w
               + a1.x * w1.x + a1.y * w1.y + a1.z * w1.z + a1.w * w1.w;
      accB[c] += b0.x * w0.x + b0.y * w0.y + b0.z * w0.z + b0.w * w0.w
               + b1v.x * w1.x + b1v.y * w1.y + b1v.z * w1.z + b1v.w * w1.w;
    }
  }
  float* __restrict__ P = half ? Pdst : Psrc;
  float4* poA = (float4*)(P + (size_t)nodeA * 32);
#pragma unroll
  for (int q = 0; q < 7; q++)
    poA[q] = make_float4(accA[q * 4], accA[q * 4 + 1], accA[q * 4 + 2], accA[q * 4 + 3]);
  poA[7] = make_float4(0.f, 0.f, 0.f, 0.f);
  if (vB) {
    float4* poB = (float4*)(P + (size_t)nodeB * 32);
#pragma unroll
    for (int q = 0; q < 7; q++)
      poB[q] = make_float4(accB[q * 4], accB[q * 4 + 1], accB[q * 4 + 2], accB[q * 4 + 3]);
    poB[7] = make_float4(0.f, 0.f, 0.f, 0.f);
  }
}

// K2: round-9 structure exactly (2 tiles/block, grid 1172 — measured 73us).
__global__ __launch_bounds__(256)
void k2_edge(const float* __restrict__ Psrc, const float* __restrict__ Pdst,
             const float* __restrict__ ef,
             const int* __restrict__ src, const int* __restrict__ dst,
             const float* __restrict__ W1, const float* __restrict__ b1,
             float* __restrict__ y1, float* __restrict__ stats, int E) {
  __shared__ float lw[28][12];
  __shared__ float lb[28];
  __shared__ float tile[7168];
  __shared__ float lsum[8][28], lssq[8][28];
  const int tid = threadIdx.x;
  for (int i = tid; i < 336; i += 256) lw[i / 12][i % 12] = W1[(i / 12) * 268 + 256 + (i % 12)];
  if (tid < 28) lb[tid] = b1[tid];
  if (tid < 224) { lsum[tid / 28][tid % 28] = 0.f; lssq[tid / 28][tid % 28] = 0.f; }
  __syncthreads();
  float sx = 0.f, sy = 0.f, sz = 0.f, sw = 0.f;
  float qx = 0.f, qy = 0.f, qz = 0.f, qw = 0.f;
  for (int t = 0; t < 2; t++) {
    const int base = (blockIdx.x * 2 + t) * 256;
    const int e = base + tid;
    if (e < E) {
      const int s = src[e], d = dst[e];
      const float4* __restrict__ pa4 = (const float4*)(Psrc + (size_t)s * 32);
      const float4* __restrict__ pb4 = (const float4*)(Pdst + (size_t)d * 32);
      const float4* __restrict__ e4 = (const float4*)(ef + (size_t)e * 12);
      float f[12];
#pragma unroll
      for (int q = 0; q < 3; q++) {
        const float4 v = e4[q];
        f[q * 4] = v.x; f[q * 4 + 1] = v.y; f[q * 4 + 2] = v.z; f[q * 4 + 3] = v.w;
      }
      float* tr = &tile[tid * 28];
#pragma unroll
      for (int q = 0; q < 7; q++) {
        const float4 ta = pa4[q];
        const float4 tb = pb4[q];
        float vv[4];
#pragma unroll
        for (int i2 = 0; i2 < 4; i2++) {
          const int c = q * 4 + i2;
          const float4* lw4 = (const float4*)(&lw[c][0]);
          const float4 w0 = lw4[0], w1 = lw4[1], w2 = lw4[2];
          vv[i2] = lb[c]
              + f[0] * w0.x + f[1] * w0.y + f[2] * w0.z + f[3] * w0.w
              + f[4] * w1.x + f[5] * w1.y + f[6] * w1.z + f[7] * w1.w
              + f[8] * w2.x + f[9] * w2.y + f[10] * w2.z + f[11] * w2.w;
        }
        *(float4*)&tr[q * 4] = make_float4(vv[0] + ta.x + tb.x, vv[1] + ta.y + tb.y,
                                           vv[2] + ta.z + tb.z, vv[3] + ta.w + tb.w);
      }
    }
    __syncthreads();
    const int nval = min(256, E - base) * 28;
    if (tid < 224) {
      const size_t gbase = (size_t)base * 28;
#pragma unroll
      for (int i = 0; i < 8; i++) {
        const int jl = tid * 4 + i * 896;
        if (jl < nval) {
          const float4 v = *(const float4*)&tile[jl];
          *(float4*)(y1 + gbase + jl) = v;
          sx += v.x; sy += v.y; sz += v.z; sw += v.w;
          qx += v.x * v.x; qy += v.y * v.y; qz += v.z * v.z; qw += v.w * v.w;
        }
      }
    }
    __syncthreads();
  }
  if (tid < 224) {
    const int c0 = (tid * 4) % 28, a8 = tid / 28;
    atomicAdd(&lsum[a8][c0], sx);     atomicAdd(&lssq[a8][c0], qx);
    atomicAdd(&lsum[a8][c0 + 1], sy); atomicAdd(&lssq[a8][c0 + 1], qy);
    atomicAdd(&lsum[a8][c0 + 2], sz); atomicAdd(&lssq[a8][c0 + 2], qz);
    atomicAdd(&lsum[a8][c0 + 3], sw); atomicAdd(&lssq[a8][c0 + 3], qw);
  }
  __syncthreads();
  if (tid < 28) {
    float S = 0.f, Q = 0.f;
#pragma unroll
    for (int a = 0; a < 8; a++) { S += lsum[a][tid]; Q += lssq[a][tid]; }
    atomicAdd(&stats[tid], S);
    atomicAdd(&stats[28 + tid], Q);
  }
}

// K4 v2: register-prefetch double-buffer (T14 async-stage). Both tiles'
// global loads issue at kernel entry (16 float4 in flight); regs->LDS, then
// barrier/compute per tile. Tile B's HBM latency hides under tile A's
// compute. Old version serialized stage->barrier->compute per tile at ~4.6
// blocks/CU -> every tile paid full load latency. 3 barriers (was 4).
// Head computes BN1 scale/shift per-block (fused k3).
__global__ __launch_bounds__(256)
void k4_l2(const float* __restrict__ y1, const float* __restrict__ statsRO,
           const float* __restrict__ W2, const float* __restrict__ b2,
           const float* __restrict__ g1, const float* __restrict__ be1,
           float* __restrict__ y2, float* __restrict__ statsW,
           int E, float invE) {
  __shared__ float tile[7168];
  __shared__ float4 w2q[8][7];
  __shared__ float scs[28], shs[28];
  __shared__ float lb2[8];
  __shared__ float redS[4][16];
  const int tid = threadIdx.x;
  const int baseA = blockIdx.x * 512;
  const int baseB = baseA + 256;
  const int nvalA = min(256, E - baseA) * 28;   // may be <= 0
  const int nvalB = min(256, E - baseB) * 28;

  // issue BOTH tiles' loads immediately (prefetch into registers)
  float4 rA[8], rB[8];
  if (tid < 224) {
#pragma unroll
    for (int i = 0; i < 8; i++) {
      const int jl = tid * 4 + i * 896;
      rA[i] = make_float4(0.f, 0.f, 0.f, 0.f);
      rB[i] = make_float4(0.f, 0.f, 0.f, 0.f);
      if (jl < nvalA) rA[i] = *(const float4*)(y1 + (size_t)baseA * 28 + jl);
      if (jl < nvalB) rB[i] = *(const float4*)(y1 + (size_t)baseB * 28 + jl);
    }
  }

  // head: weights + BN1 finalize (overlaps with loads in flight)
  if (tid < 56) {
    w2q[tid / 7][tid % 7] = *(const float4*)(W2 + (tid / 7) * 28 + (tid % 7) * 4);
  } else if (tid >= 64 && tid < 92) {
    const int c = tid - 64;
    const float mean = statsRO[c] * invE;
    const float var = statsRO[28 + c] * invE - mean * mean;
    const float sc = g1[c] * rsqrtf(var + BN_EPS);
    scs[c] = sc;
    shs[c] = be1[c] - mean * sc;
  } else if (tid >= 96 && tid < 104) {
    lb2[tid - 96] = b2[tid - 96];
  }

  // tile A: regs -> LDS
  if (tid < 224) {
#pragma unroll
    for (int i = 0; i < 8; i++) {
      const int jl = tid * 4 + i * 896;
      if (jl < nvalA) *(float4*)&tile[jl] = rA[i];
    }
  }

  float as[8], aq[8];
#pragma unroll
  for (int o = 0; o < 8; o++) { as[o] = 0.f; aq[o] = 0.f; }

  __syncthreads();   // tile A + head ready

  // compute tile A
  {
    const int e = baseA + tid;
    if (e < E) {
      float accv[8];
#pragma unroll
      for (int o = 0; o < 8; o++) accv[o] = lb2[o];
      const float* tr = &tile[tid * 28];
#pragma unroll
      for (int q = 0; q < 7; q++) {
        const float4 sv = *(const float4*)&tr[q * 4];
        const float4 sc = *(const float4*)&scs[q * 4];
        const float4 sh = *(const float4*)&shs[q * 4];
        const float s0 = fmaxf(sv.x * sc.x + sh.x, 0.f);
        const float s1 = fmaxf(sv.y * sc.y + sh.y, 0.f);
        const float s2 = fmaxf(sv.z * sc.z + sh.z, 0.f);
        const float s3 = fmaxf(sv.w * sc.w + sh.w, 0.f);
#pragma unroll
        for (int o = 0; o < 8; o++) {
          const float4 w = w2q[o][q];
          accv[o] += s0 * w.x + s1 * w.y + s2 * w.z + s3 * w.w;
        }
      }
      float4* yo = (float4*)(y2 + (size_t)e * 8);
      yo[0] = make_float4(accv[0], accv[1], accv[2], accv[3]);
      yo[1] = make_float4(accv[4], accv[5], accv[6], accv[7]);
#pragma unroll
      for (int o = 0; o < 8; o++) { as[o] += accv[o]; aq[o] += accv[o] * accv[o]; }
    }
  }

  __syncthreads();   // tile A reads done

  // tile B: regs -> LDS (data long since arrived)
  if (tid < 224) {
#pragma unroll
    for (int i = 0; i < 8; i++) {
      const int jl = tid * 4 + i * 896;
      if (jl < nvalB) *(float4*)&tile[jl] = rB[i];
    }
  }

  __syncthreads();   // tile B ready

  // compute tile B
  {
    const int e = baseB + tid;
    if (e < E) {
      float accv[8];
#pragma unroll
      for (int o = 0; o < 8; o++) accv[o] = lb2[o];
      const float* tr = &tile[tid * 28];
#pragma unroll
      for (int q = 0; q < 7; q++) {
        const float4 sv = *(const float4*)&tr[q * 4];
        const float4 sc = *(const float4*)&scs[q * 4];
        const float4 sh = *(const float4*)&shs[q * 4];
        const float s0 = fmaxf(sv.x * sc.x + sh.x, 0.f);
        const float s1 = fmaxf(sv.y * sc.y + sh.y, 0.f);
        const float s2 = fmaxf(sv.z * sc.z + sh.z, 0.f);
        const float s3 = fmaxf(sv.w * sc.w + sh.w, 0.f);
#pragma unroll
        for (int o = 0; o < 8; o++) {
          const float4 w = w2q[o][q];
          accv[o] += s0 * w.x + s1 * w.y + s2 * w.z + s3 * w.w;
        }
      }
      float4* yo = (float4*)(y2 + (size_t)e * 8);
      yo[0] = make_float4(accv[0], accv[1], accv[2], accv[3]);
      yo[1] = make_float4(accv[4], accv[5], accv[6], accv[7]);
#pragma unroll
      for (int o = 0; o < 8; o++) { as[o] += accv[o]; aq[o] += accv[o] * accv[o]; }
    }
  }

  // stats reduce
#pragma unroll
  for (int o = 0; o < 8; o++) {
    for (int off = 32; off; off >>= 1) {
      as[o] += __shfl_down(as[o], off);
      aq[o] += __shfl_down(aq[o], off);
    }
  }
  const int wave = tid >> 6, lane = tid & 63;
  if (lane == 0) {
#pragma unroll
    for (int o = 0; o < 8; o++) { redS[wave][o] = as[o]; redS[wave][8 + o] = aq[o]; }
  }
  __syncthreads();
  if (tid < 16) {
    atomicAdd(&statsW[56 + tid], redS[0][tid] + redS[1][tid] + redS[2][tid] + redS[3][tid]);
  }
}

// K6: head computes BN2 scale/shift per-block (fused k5), then
// out = relu(BN2(y2)) @ W3.T + b3
__global__ void k6_l3(const float* __restrict__ y2, const float* __restrict__ stats,
                      const float* __restrict__ g2, const float* __restrict__ be2,
                      const float* __restrict__ W3, const float* __restrict__ b3,
                      float* __restrict__ out, int E, float invE) {
  __shared__ float sc2[8], sh2[8], w3[8];
  __shared__ float b3s;
  if (threadIdx.x < 8) {
    const int c = threadIdx.x;
    const float mean = stats[56 + c] * invE;
    const float var = stats[64 + c] * invE - mean * mean;
    const float sc = g2[c] * rsqrtf(var + BN_EPS);
    sc2[c] = sc;
    sh2[c] = be2[c] - mean * sc;
    w3[c] = W3[c];
    if (c == 0) b3s = b3[0];
  }
  __syncthreads();
  const int e = blockIdx.x * blockDim.x + threadIdx.x;
  if (e >= E) return;
  const float4* p = (const float4*)(y2 + (size_t)e * 8);
  float4 a = p[0], b4 = p[1];
  float v[8] = {a.x, a.y, a.z, a.w, b4.x, b4.y, b4.z, b4.w};
  float acc = b3s;
#pragma unroll
  for (int o = 0; o < 8; o++) {
    float s = fmaxf(v[o] * sc2[o] + sh2[o], 0.f);
    acc += w3[o] * s;
  }
  out[e] = acc;
}

extern "C" void kernel_launch(void* const* d_in, const int* in_sizes, int n_in,
                              void* d_out, int out_size, void* d_ws, size_t ws_size,
                              hipStream_t stream) {
  const float* h   = (const float*)d_in[0];
  const float* ef  = (const float*)d_in[1];
  const int* src   = (const int*)d_in[2];
  const int* dst   = (const int*)d_in[3];
  const float* W1  = (const float*)d_in[4];
  const float* b1  = (const float*)d_in[5];
  const float* g1  = (const float*)d_in[6];
  const float* be1 = (const float*)d_in[7];
  const float* W2  = (const float*)d_in[8];
  const float* b2  = (const float*)d_in[9];
  const float* g2  = (const float*)d_in[10];
  const float* be2 = (const float*)d_in[11];
  const float* W3  = (const float*)d_in[12];
  const float* b3  = (const float*)d_in[13];
  float* out = (float*)d_out;

  const int N = in_sizes[0] / 128;
  const int E = in_sizes[2];
  const float invE = 1.0f / (float)E;

  float* ws = (float*)d_ws;
  float* stats = ws;
  float* Psrc = ws + 256;
  float* y1 = Psrc + (size_t)N * 32;
  float* y2 = y1 + (size_t)E * 28;
  float* Pdst = y2;

  const int nodeBlocks = (N + 255) / 256;
  const int nTiles = (E + 255) / 256;   // 2344
  const int nPair = (nTiles + 1) / 2;   // 1172
  k1_proj<<<nodeBlocks * 2, 128, 0, stream>>>(h, W1, Psrc, Pdst, stats, N);
  k2_edge<<<nPair, 256, 0, stream>>>(Psrc, Pdst, ef, src, dst, W1, b1, y1, stats, E);
  k4_l2<<<nPair, 256, 0, stream>>>(y1, stats, W2, b2, g1, be1, y2, stats, E, invE);
  k6_l3<<<nTiles, 256, 0, stream>>>(y2, stats, g2, be2, W3, b3, out, E, invE);
}